// Round 5
// baseline (240.750 us; speedup 1.0000x reference)
//
#include <hip/hip_runtime.h>

// R5: attn reverted to R3 orientation (A=Q,B=K -> cross-lane coalesced dep/out)
// but with 512-thread blocks (8 waves, 128 q-rows) for 2x occupancy and half
// the K staging traffic. Score scale 0.9/sqrt(64) folded into Q at proj
// epilogue. proj: 128x128 LDS-tiled 4-wave MFMA GEMM (R4). prep unchanged.

typedef _Float16 f16;
typedef _Float16 f16x4 __attribute__((ext_vector_type(4)));
typedef _Float16 f16x8 __attribute__((ext_vector_type(8)));
typedef float    f32x4 __attribute__((ext_vector_type(4)));

#define NTOK   512
#define DMODEL 768
#define BATCH  8
#define NHEAD  12
#define NEGV   (-1e9f)
#define KPAD   72   // LDS row stride in halfs (144 B): 16B-aligned, 2-way banks

// ---------------------------------------------------------------------------
// prep: blocks [0,3072) convert X fp32->f16; blocks [3072,4224) transpose
// Wq/Wk 32x32 tiles -> Wt[n][k] f16 (rows 0-767 Wq^T, 768-1535 Wk^T).
__global__ __launch_bounds__(256)
void prep_kernel(const float* __restrict__ X, f16* __restrict__ Xh,
                 const float* __restrict__ Wq, const float* __restrict__ Wk,
                 f16* __restrict__ Wt) {
    const int bx = blockIdx.x;
    if (bx < 3072) {
        const size_t i = ((size_t)bx * 256 + threadIdx.x) * 4;
        float4 v = *(const float4*)&X[i];
        f16x4 h = { (f16)v.x, (f16)v.y, (f16)v.z, (f16)v.w };
        *(f16x4*)&Xh[i] = h;
    } else {
        __shared__ float tile[32][33];
        const int id = bx - 3072;
        const int kb = (id % 24) * 32;
        const int nb = (id / 24) * 32;          // combined n in [0,1536)
        const float* __restrict__ W = (nb < 768) ? Wq : Wk;
        const int nc = (nb < 768) ? nb : nb - 768;
        const int tx = threadIdx.x & 31, ty = threadIdx.x >> 5;
        #pragma unroll
        for (int i = 0; i < 4; ++i)
            tile[ty + i*8][tx] = W[(size_t)(kb + ty + i*8) * DMODEL + nc + tx];
        __syncthreads();
        #pragma unroll
        for (int i = 0; i < 4; ++i)
            Wt[(size_t)(nb + ty + i*8) * DMODEL + kb + tx] = (f16)tile[tx][ty + i*8];
    }
}

// ---------------------------------------------------------------------------
// proj: 128x128 tile per block, 4 waves in 2x2 quadrants, BK=64 LDS-staged.
// QK[4096][1536] = Xh * Wt^T + bias; Q columns (<768) pre-scaled by 0.9/8.
// grid (32, 12), block 256.
__global__ __launch_bounds__(256)
void proj_mfma(const f16* __restrict__ Xh, const f16* __restrict__ Wt,
               const float* __restrict__ bq, const float* __restrict__ bk,
               f16* __restrict__ QK) {
    const int m0 = blockIdx.x * 128;
    const int n0 = blockIdx.y * 128;
    const int tid = threadIdx.x;
    const int wid = tid >> 6, l = tid & 63;
    const int l15 = l & 15, quad = l >> 4;
    const int wm = (wid & 1) * 64;
    const int wn = (wid >> 1) * 64;

    __shared__ f16 As[128 * KPAD];   // 18 KB
    __shared__ f16 Bs[128 * KPAD];   // 18 KB

    f32x4 acc[4][4];
    #pragma unroll
    for (int i = 0; i < 4; ++i)
        #pragma unroll
        for (int j = 0; j < 4; ++j) acc[i][j] = (f32x4){0.f, 0.f, 0.f, 0.f};

    const int srow = tid >> 1;
    const int scol = (tid & 1) * 32;

    for (int kt = 0; kt < DMODEL; kt += 64) {
        const f16* __restrict__ Asrc = Xh + (size_t)(m0 + srow) * DMODEL + kt + scol;
        const f16* __restrict__ Bsrc = Wt + (size_t)(n0 + srow) * DMODEL + kt + scol;
        #pragma unroll
        for (int j = 0; j < 4; ++j) {
            f16x8 av = *(const f16x8*)(Asrc + j * 8);
            *(f16x8*)&As[srow * KPAD + scol + j * 8] = av;
        }
        #pragma unroll
        for (int j = 0; j < 4; ++j) {
            f16x8 bv = *(const f16x8*)(Bsrc + j * 8);
            *(f16x8*)&Bs[srow * KPAD + scol + j * 8] = bv;
        }
        __syncthreads();
        #pragma unroll
        for (int ks = 0; ks < 2; ++ks) {
            f16x8 a[4], b[4];
            #pragma unroll
            for (int mi = 0; mi < 4; ++mi)
                a[mi] = *(f16x8*)&As[(wm + mi*16 + l15) * KPAD + ks*32 + quad*8];
            #pragma unroll
            for (int ni = 0; ni < 4; ++ni)
                b[ni] = *(f16x8*)&Bs[(wn + ni*16 + l15) * KPAD + ks*32 + quad*8];
            #pragma unroll
            for (int mi = 0; mi < 4; ++mi)
                #pragma unroll
                for (int ni = 0; ni < 4; ++ni)
                    acc[mi][ni] = __builtin_amdgcn_mfma_f32_16x16x32_f16(
                        a[mi], b[ni], acc[mi][ni], 0, 0, 0);
        }
        __syncthreads();
    }

    const float SC = (1.0f - 0.1f) / 8.0f;   // (1-d_weight)/sqrt(dk) -> into Q
    #pragma unroll
    for (int ni = 0; ni < 4; ++ni) {
        const int col = n0 + wn + ni * 16 + l15;
        const bool isQ = (col < 768);
        const float bv = isQ ? bq[col] : bk[col - 768];
        const float sc = isQ ? SC : 1.0f;
        #pragma unroll
        for (int mi = 0; mi < 4; ++mi)
            #pragma unroll
            for (int r = 0; r < 4; ++r) {
                const int row = m0 + wm + mi * 16 + quad * 4 + r;
                QK[(size_t)row * 1536 + col] = (f16)((acc[mi][ni][r] + bv) * sc);
            }
    }
}

// ---------------------------------------------------------------------------
// attn: block = 8 waves = 128 q rows of one (b,h); K-head staged in LDS once.
// A = Q-frag (m = q-row), B = K-frag (n = k-token) -> lane owns col t*16+l15:
// cross-lane coalesced dep loads and out stores. grid (4,12,8), block 512.
__global__ __launch_bounds__(512, 4)
void attn_mfma(const f16* __restrict__ QK, const float* __restrict__ dep,
               const int* __restrict__ mask, float* __restrict__ out) {
    const int qt = blockIdx.x, h = blockIdx.y, b = blockIdx.z;
    const int tid = threadIdx.x;
    const int wid = tid >> 6, l = tid & 63;
    const int l15 = l & 15, quad = l >> 4;
    const int q0 = qt * 128 + wid * 16;

    __shared__ f16 Ks[NTOK * KPAD];   // 72 KB

    // stage K-head: 512 tokens x 8 chunks of f16x8; 8 chunks per thread
    {
        const f16* __restrict__ Ksrc = QK + (size_t)b * NTOK * 1536 + 768 + h * 64;
        #pragma unroll
        for (int c = 0; c < 8; ++c) {
            const int chunk = tid + c * 512;
            const int token = chunk >> 3;
            const int part  = chunk & 7;
            f16x8 v = *(const f16x8*)(Ksrc + (size_t)token * 1536 + part * 8);
            *(f16x8*)&Ks[token * KPAD + part * 8] = v;
        }
    }
    __syncthreads();

    f32x4 acc[32];
    #pragma unroll
    for (int t = 0; t < 32; ++t) acc[t] = (f32x4){0.f, 0.f, 0.f, 0.f};

    const f16* __restrict__ Qb = QK + (size_t)(b * NTOK + q0 + l15) * 1536 + h * 64 + quad * 8;
    const f16x8 qf0 = *(const f16x8*)(Qb);
    const f16x8 qf1 = *(const f16x8*)(Qb + 32);

    #pragma unroll
    for (int t = 0; t < 32; ++t) {
        f16x8 k0 = *(f16x8*)&Ks[(t * 16 + l15) * KPAD + quad * 8];
        acc[t] = __builtin_amdgcn_mfma_f32_16x16x32_f16(qf0, k0, acc[t], 0, 0, 0);
        f16x8 k1 = *(f16x8*)&Ks[(t * 16 + l15) * KPAD + 32 + quad * 8];
        acc[t] = __builtin_amdgcn_mfma_f32_16x16x32_f16(qf1, k1, acc[t], 0, 0, 0);
    }

    // blend with dep bias + mask (Q already carries the 0.9/8 scale)
    const float DW = 0.1f;
    const float* __restrict__ deprow = dep + ((size_t)b * NTOK + q0 + quad * 4) * NTOK;
    const int*   __restrict__ mrow   = mask + b * NTOK;
    #pragma unroll
    for (int t = 0; t < 32; ++t) {
        const int col = t * 16 + l15;
        const int mv = mrow[col];
        #pragma unroll
        for (int r = 0; r < 4; ++r) {
            const float dv = deprow[(size_t)r * NTOK + col];
            const float s = acc[t][r] + DW * dv;
            acc[t][r] = mv ? s : NEGV;
        }
    }

    // softmax: each q-row lives in 16 lanes (fixed quad) x 32 regs
    float rmax[4] = {NEGV, NEGV, NEGV, NEGV};
    #pragma unroll
    for (int t = 0; t < 32; ++t)
        #pragma unroll
        for (int r = 0; r < 4; ++r) rmax[r] = fmaxf(rmax[r], acc[t][r]);
    #pragma unroll
    for (int r = 0; r < 4; ++r) {
        rmax[r] = fmaxf(rmax[r], __shfl_xor(rmax[r], 1));
        rmax[r] = fmaxf(rmax[r], __shfl_xor(rmax[r], 2));
        rmax[r] = fmaxf(rmax[r], __shfl_xor(rmax[r], 4));
        rmax[r] = fmaxf(rmax[r], __shfl_xor(rmax[r], 8));
    }
    float rsum[4] = {0.f, 0.f, 0.f, 0.f};
    #pragma unroll
    for (int t = 0; t < 32; ++t)
        #pragma unroll
        for (int r = 0; r < 4; ++r) {
            const float e = __expf(acc[t][r] - rmax[r]);
            acc[t][r] = e;
            rsum[r] += e;
        }
    #pragma unroll
    for (int r = 0; r < 4; ++r) {
        rsum[r] += __shfl_xor(rsum[r], 1);
        rsum[r] += __shfl_xor(rsum[r], 2);
        rsum[r] += __shfl_xor(rsum[r], 4);
        rsum[r] += __shfl_xor(rsum[r], 8);
    }
    float inv[4];
    #pragma unroll
    for (int r = 0; r < 4; ++r) inv[r] = 1.0f / rsum[r];

    float* __restrict__ orow = out + ((size_t)((b * NHEAD + h) * NTOK) + q0 + quad * 4) * NTOK;
    #pragma unroll
    for (int t = 0; t < 32; ++t)
        #pragma unroll
        for (int r = 0; r < 4; ++r)
            orow[(size_t)r * NTOK + t * 16 + l15] = acc[t][r] * inv[r];
}

// ---------------------------------------------------------------------------
extern "C" void kernel_launch(void* const* d_in, const int* in_sizes, int n_in,
                              void* d_out, int out_size, void* d_ws, size_t ws_size,
                              hipStream_t stream) {
    const float* X    = (const float*)d_in[0];
    const int*   mask = (const int*)  d_in[1];
    const float* dep  = (const float*)d_in[2];
    const float* Wq   = (const float*)d_in[3];
    const float* bq   = (const float*)d_in[4];
    const float* Wk   = (const float*)d_in[5];
    const float* bk   = (const float*)d_in[6];
    float* out = (float*)d_out;

    f16* Xh = (f16*)d_ws;                                  // 4096*768
    f16* Wt = Xh + (size_t)BATCH * NTOK * DMODEL;          // 1536*768
    f16* QK = Wt + (size_t)1536 * DMODEL;                  // 4096*1536

    prep_kernel<<<dim3(3072 + 1152), 256, 0, stream>>>(X, Xh, Wq, Wk, Wt);
    proj_mfma<<<dim3(4096 / 128, 1536 / 128), 256, 0, stream>>>(Xh, Wt, bq, bk, QK);
    attn_mfma<<<dim3(NTOK / 128, NHEAD, BATCH), 512, 0, stream>>>(QK, dep, mask, out);
}

// Round 6
// 186.385 us; speedup vs baseline: 1.2917x; 1.2917x over previous
//
#include <hip/hip_runtime.h>

// R6: attn block = (b, 16 q-rows, 6 heads) x 384 thr (1 wave/head).
//  - dep tile (16x512 f32) staged in LDS once, shared by all 6 heads (/6 HBM dep traffic)
//  - K-fragments read from global/L2 (R2-proven pattern; no K LDS)
//  - epilogue: per-wave LDS transpose -> float4 stores covering full 128B lines
//  - launch_bounds(384,2): 256-VGPR cap, NO spills (R5's (512,4) cap at 128 spilled acc)
// proj/prep unchanged from R5 (128x128 LDS-tiled MFMA GEMM; Q pre-scaled by 0.9/8).

typedef _Float16 f16;
typedef _Float16 f16x4 __attribute__((ext_vector_type(4)));
typedef _Float16 f16x8 __attribute__((ext_vector_type(8)));
typedef float    f32x4 __attribute__((ext_vector_type(4)));

#define NTOK   512
#define DMODEL 768
#define BATCH  8
#define NHEAD  12
#define NEGV   (-1e9f)
#define KPAD   72    // proj LDS row stride (halfs)
#define DEPS   516   // dep LDS row stride (floats): quad offset 16 banks -> 2-way free
#define OUTS   68    // out-chunk LDS row stride (floats)

// ---------------------------------------------------------------------------
// prep: blocks [0,3072) convert X fp32->f16; blocks [3072,4224) transpose
// Wq/Wk 32x32 tiles -> Wt[n][k] f16 (rows 0-767 Wq^T, 768-1535 Wk^T).
__global__ __launch_bounds__(256)
void prep_kernel(const float* __restrict__ X, f16* __restrict__ Xh,
                 const float* __restrict__ Wq, const float* __restrict__ Wk,
                 f16* __restrict__ Wt) {
    const int bx = blockIdx.x;
    if (bx < 3072) {
        const size_t i = ((size_t)bx * 256 + threadIdx.x) * 4;
        float4 v = *(const float4*)&X[i];
        f16x4 h = { (f16)v.x, (f16)v.y, (f16)v.z, (f16)v.w };
        *(f16x4*)&Xh[i] = h;
    } else {
        __shared__ float tile[32][33];
        const int id = bx - 3072;
        const int kb = (id % 24) * 32;
        const int nb = (id / 24) * 32;
        const float* __restrict__ W = (nb < 768) ? Wq : Wk;
        const int nc = (nb < 768) ? nb : nb - 768;
        const int tx = threadIdx.x & 31, ty = threadIdx.x >> 5;
        #pragma unroll
        for (int i = 0; i < 4; ++i)
            tile[ty + i*8][tx] = W[(size_t)(kb + ty + i*8) * DMODEL + nc + tx];
        __syncthreads();
        #pragma unroll
        for (int i = 0; i < 4; ++i)
            Wt[(size_t)(nb + ty + i*8) * DMODEL + kb + tx] = (f16)tile[tx][ty + i*8];
    }
}

// ---------------------------------------------------------------------------
// proj: 128x128 tile per block, 4 waves in 2x2 quadrants, BK=64 LDS-staged.
// QK[4096][1536] = Xh * Wt^T + bias; Q columns (<768) pre-scaled by 0.9/8.
__global__ __launch_bounds__(256)
void proj_mfma(const f16* __restrict__ Xh, const f16* __restrict__ Wt,
               const float* __restrict__ bq, const float* __restrict__ bk,
               f16* __restrict__ QK) {
    const int m0 = blockIdx.x * 128;
    const int n0 = blockIdx.y * 128;
    const int tid = threadIdx.x;
    const int wid = tid >> 6, l = tid & 63;
    const int l15 = l & 15, quad = l >> 4;
    const int wm = (wid & 1) * 64;
    const int wn = (wid >> 1) * 64;

    __shared__ f16 As[128 * KPAD];
    __shared__ f16 Bs[128 * KPAD];

    f32x4 acc[4][4];
    #pragma unroll
    for (int i = 0; i < 4; ++i)
        #pragma unroll
        for (int j = 0; j < 4; ++j) acc[i][j] = (f32x4){0.f, 0.f, 0.f, 0.f};

    const int srow = tid >> 1;
    const int scol = (tid & 1) * 32;

    for (int kt = 0; kt < DMODEL; kt += 64) {
        const f16* __restrict__ Asrc = Xh + (size_t)(m0 + srow) * DMODEL + kt + scol;
        const f16* __restrict__ Bsrc = Wt + (size_t)(n0 + srow) * DMODEL + kt + scol;
        #pragma unroll
        for (int j = 0; j < 4; ++j) {
            f16x8 av = *(const f16x8*)(Asrc + j * 8);
            *(f16x8*)&As[srow * KPAD + scol + j * 8] = av;
        }
        #pragma unroll
        for (int j = 0; j < 4; ++j) {
            f16x8 bv = *(const f16x8*)(Bsrc + j * 8);
            *(f16x8*)&Bs[srow * KPAD + scol + j * 8] = bv;
        }
        __syncthreads();
        #pragma unroll
        for (int ks = 0; ks < 2; ++ks) {
            f16x8 a[4], b[4];
            #pragma unroll
            for (int mi = 0; mi < 4; ++mi)
                a[mi] = *(f16x8*)&As[(wm + mi*16 + l15) * KPAD + ks*32 + quad*8];
            #pragma unroll
            for (int ni = 0; ni < 4; ++ni)
                b[ni] = *(f16x8*)&Bs[(wn + ni*16 + l15) * KPAD + ks*32 + quad*8];
            #pragma unroll
            for (int mi = 0; mi < 4; ++mi)
                #pragma unroll
                for (int ni = 0; ni < 4; ++ni)
                    acc[mi][ni] = __builtin_amdgcn_mfma_f32_16x16x32_f16(
                        a[mi], b[ni], acc[mi][ni], 0, 0, 0);
        }
        __syncthreads();
    }

    const float SC = (1.0f - 0.1f) / 8.0f;
    #pragma unroll
    for (int ni = 0; ni < 4; ++ni) {
        const int col = n0 + wn + ni * 16 + l15;
        const bool isQ = (col < 768);
        const float bv = isQ ? bq[col] : bk[col - 768];
        const float sc = isQ ? SC : 1.0f;
        #pragma unroll
        for (int mi = 0; mi < 4; ++mi)
            #pragma unroll
            for (int r = 0; r < 4; ++r) {
                const int row = m0 + wm + mi * 16 + quad * 4 + r;
                QK[(size_t)row * 1536 + col] = (f16)((acc[mi][ni][r] + bv) * sc);
            }
    }
}

// ---------------------------------------------------------------------------
// attn: block = (b, qt, head-group); 384 thr = 6 waves, wave w -> head hg*6+w,
// 16 q-rows. dep tile in LDS shared by all 6 heads; K from L2; LDS-transposed
// coalesced epilogue. grid (32, 2, 8) = 512 blocks.
__global__ __launch_bounds__(384, 2)
void attn_mfma(const f16* __restrict__ QK, const float* __restrict__ dep,
               const int* __restrict__ mask, float* __restrict__ out) {
    const int qt = blockIdx.x;        // 0..31
    const int hg = blockIdx.y;        // 0..1
    const int b  = blockIdx.z;        // 0..7
    const int tid = threadIdx.x;
    const int wid = tid >> 6;         // 0..5
    const int l   = tid & 63;
    const int l15 = l & 15, quad = l >> 4;
    const int h  = hg * 6 + wid;
    const int q0 = qt * 16;

    __shared__ float depL[16 * DEPS];        // 33.0 KB
    __shared__ float outL[6 * 16 * OUTS];    // 26.1 KB

    // stage dep tile: 16 rows x 512 cols (2048 float4, block-cooperative)
    {
        const float* __restrict__ src = dep + ((size_t)b * NTOK + q0) * NTOK;
        #pragma unroll
        for (int i = 0; i < 6; ++i) {
            const int idx = tid + i * 384;
            if (idx < 2048) {
                const int row = idx >> 7, c4 = idx & 127;
                float4 v = *(const float4*)&src[(size_t)row * NTOK + c4 * 4];
                *(float4*)&depL[row * DEPS + c4 * 4] = v;
            }
        }
    }
    __syncthreads();

    f32x4 acc[32];
    #pragma unroll
    for (int t = 0; t < 32; ++t) acc[t] = (f32x4){0.f, 0.f, 0.f, 0.f};

    // Q fragment: A[m=l15][k=quad*8+j]; Q pre-scaled by 0.9/8 in proj
    const f16* __restrict__ Qb = QK + (size_t)(b * NTOK + q0 + l15) * 1536 + h * 64 + quad * 8;
    const f16x8 qf0 = *(const f16x8*)(Qb);
    const f16x8 qf1 = *(const f16x8*)(Qb + 32);

    // K fragments from global (L2-resident): B[n=l15][k=quad*8+j]
    const f16* __restrict__ Kb = QK + (size_t)(b * NTOK + l15) * 1536 + 768 + h * 64 + quad * 8;
    #pragma unroll
    for (int t = 0; t < 32; ++t) {
        f16x8 k0 = *(const f16x8*)(Kb + (size_t)(t * 16) * 1536);
        acc[t] = __builtin_amdgcn_mfma_f32_16x16x32_f16(qf0, k0, acc[t], 0, 0, 0);
        f16x8 k1 = *(const f16x8*)(Kb + (size_t)(t * 16) * 1536 + 32);
        acc[t] = __builtin_amdgcn_mfma_f32_16x16x32_f16(qf1, k1, acc[t], 0, 0, 0);
    }

    // blend (dep from LDS) + mask
    const float DW = 0.1f;
    const int* __restrict__ mrow = mask + b * NTOK;
    #pragma unroll
    for (int t = 0; t < 32; ++t) {
        const int col = t * 16 + l15;
        const int mv = mrow[col];
        #pragma unroll
        for (int r = 0; r < 4; ++r) {
            const float dv = depL[(quad * 4 + r) * DEPS + col];
            const float s = acc[t][r] + DW * dv;
            acc[t][r] = mv ? s : NEGV;
        }
    }

    // softmax: q-row = (quad*4+r), lives in the 16 l15-lanes of this quad
    float rmax[4] = {NEGV, NEGV, NEGV, NEGV};
    #pragma unroll
    for (int t = 0; t < 32; ++t)
        #pragma unroll
        for (int r = 0; r < 4; ++r) rmax[r] = fmaxf(rmax[r], acc[t][r]);
    #pragma unroll
    for (int r = 0; r < 4; ++r) {
        rmax[r] = fmaxf(rmax[r], __shfl_xor(rmax[r], 1));
        rmax[r] = fmaxf(rmax[r], __shfl_xor(rmax[r], 2));
        rmax[r] = fmaxf(rmax[r], __shfl_xor(rmax[r], 4));
        rmax[r] = fmaxf(rmax[r], __shfl_xor(rmax[r], 8));
    }
    float rsum[4] = {0.f, 0.f, 0.f, 0.f};
    #pragma unroll
    for (int t = 0; t < 32; ++t)
        #pragma unroll
        for (int r = 0; r < 4; ++r) {
            const float e = __expf(acc[t][r] - rmax[r]);
            acc[t][r] = e;
            rsum[r] += e;
        }
    #pragma unroll
    for (int r = 0; r < 4; ++r) {
        rsum[r] += __shfl_xor(rsum[r], 1);
        rsum[r] += __shfl_xor(rsum[r], 2);
        rsum[r] += __shfl_xor(rsum[r], 4);
        rsum[r] += __shfl_xor(rsum[r], 8);
    }
    float inv[4];
    #pragma unroll
    for (int r = 0; r < 4; ++r) inv[r] = 1.0f / rsum[r];

    // epilogue: per-wave LDS transpose -> fully coalesced float4 stores.
    // chunk c = 64 cols; write 16x64 to wave-private LDS, read back row-major.
    float* __restrict__ wOut = &outL[wid * 16 * OUTS];
    const size_t obase = ((size_t)((b * NHEAD + h) * NTOK) + q0) * NTOK;
    #pragma unroll
    for (int c = 0; c < 8; ++c) {
        #pragma unroll
        for (int tc = 0; tc < 4; ++tc) {
            const int t = c * 4 + tc;
            #pragma unroll
            for (int r = 0; r < 4; ++r)
                wOut[(quad * 4 + r) * OUTS + tc * 16 + l15] = acc[t][r] * inv[r];
        }
        // wave-private region: no barrier needed (lockstep + compiler lgkmcnt)
        #pragma unroll
        for (int j = 0; j < 4; ++j) {
            const int row = j * 4 + quad;
            const int c4  = l15;
            float4 v = *(float4*)&wOut[row * OUTS + c4 * 4];
            *(float4*)&out[obase + (size_t)row * NTOK + c * 64 + c4 * 4] = v;
        }
    }
}

// ---------------------------------------------------------------------------
extern "C" void kernel_launch(void* const* d_in, const int* in_sizes, int n_in,
                              void* d_out, int out_size, void* d_ws, size_t ws_size,
                              hipStream_t stream) {
    const float* X    = (const float*)d_in[0];
    const int*   mask = (const int*)  d_in[1];
    const float* dep  = (const float*)d_in[2];
    const float* Wq   = (const float*)d_in[3];
    const float* bq   = (const float*)d_in[4];
    const float* Wk   = (const float*)d_in[5];
    const float* bk   = (const float*)d_in[6];
    float* out = (float*)d_out;

    f16* Xh = (f16*)d_ws;                                  // 4096*768
    f16* Wt = Xh + (size_t)BATCH * NTOK * DMODEL;          // 1536*768
    f16* QK = Wt + (size_t)1536 * DMODEL;                  // 4096*1536

    prep_kernel<<<dim3(3072 + 1152), 256, 0, stream>>>(X, Xh, Wq, Wk, Wt);
    proj_mfma<<<dim3(4096 / 128, 1536 / 128), 256, 0, stream>>>(Xh, Wt, bq, bk, QK);
    attn_mfma<<<dim3(32, 2, BATCH), 384, 0, stream>>>(QK, dep, mask, out);
}